// Round 2
// baseline (1564.652 us; speedup 1.0000x reference)
//
#include <hip/hip_runtime.h>

typedef __attribute__((ext_vector_type(8))) short short8;
typedef __attribute__((ext_vector_type(4))) short short4v;
typedef __attribute__((ext_vector_type(4))) float f32x4;

__device__ __forceinline__ short f2bf(float f) {
  unsigned u = __float_as_uint(f);
  u += 0x7fff + ((u >> 16) & 1);   // round-to-nearest-even
  return (short)(u >> 16);
}

// async 16B global->LDS (dest = wave-uniform base + lane*16)
__device__ __forceinline__ void async16(const short* g, short* l) {
  __builtin_amdgcn_global_load_lds(
      (__attribute__((address_space(1))) unsigned int*)(g),
      (__attribute__((address_space(3))) unsigned int*)(l), 16, 0, 0);
}

// ---- one-shot weight conversion: 4 x (1024x1024) fp32 -> bf16 ----
__global__ __launch_bounds__(256) void cvt_w(const float* __restrict__ w0, const float* __restrict__ w1,
                                             const float* __restrict__ w2, const float* __restrict__ w3,
                                             short* __restrict__ o0, short* __restrict__ o1,
                                             short* __restrict__ o2, short* __restrict__ o3) {
  const int bid = blockIdx.x;
  const int seg = bid >> 9;  // 512 blocks per tensor
  const float* s = seg == 0 ? w0 : seg == 1 ? w1 : seg == 2 ? w2 : w3;
  short* d = seg == 0 ? o0 : seg == 1 ? o1 : seg == 2 ? o2 : o3;
  const int idx = ((bid & 511) * 256 + (int)threadIdx.x) * 8;
  float4 x = *(const float4*)(s + idx);
  float4 y = *(const float4*)(s + idx + 4);
  short8 t;
  t[0] = f2bf(x.x); t[1] = f2bf(x.y); t[2] = f2bf(x.z); t[3] = f2bf(x.w);
  t[4] = f2bf(y.x); t[5] = f2bf(y.y); t[6] = f2bf(y.z); t[7] = f2bf(y.w);
  *(short8*)(d + idx) = t;
}

// ---- GEMM staging helpers (128x64 K-tile) ----
__device__ __forceinline__ void ldf32(const float* src, int K, int kt, int tid, f32x4* r) {
  const int row = tid >> 4, c = (tid & 15) * 4;
  const float* p = src + (long)row * K + kt + c;
#pragma unroll
  for (int j = 0; j < 8; j++) r[j] = *(const f32x4*)(p + (long)(j * 16) * K);
}
__device__ __forceinline__ void wrf32(short* dst, int stride, int tid, const f32x4* r) {
  const int row = tid >> 4, c = (tid & 15) * 4;
#pragma unroll
  for (int j = 0; j < 8; j++) {
    short4v t;
    t[0] = f2bf(r[j][0]); t[1] = f2bf(r[j][1]); t[2] = f2bf(r[j][2]); t[3] = f2bf(r[j][3]);
    *(short4v*)&dst[(row + j * 16) * stride + c] = t;
  }
}
__device__ __forceinline__ void ldbf16(const short* src, int K, int kt, int tid, short* lds) {
  const int w = tid >> 6, l = tid & 63;
#pragma unroll
  for (int i = 0; i < 4; i++) {
    const int seg = i * 4 + w;           // 16 segments x 1KB
    const int o = seg * 1024 + l * 16;   // byte offset in 16KB tile
    const int row = o >> 7, col = (o & 127) >> 1;
    async16(src + (long)row * K + kt + col, lds + seg * 512);
  }
}

// C[m][n] = sum_k A[m][k]*B[n][k].  2-phase double-buffered, 1 barrier/K-step.
template <int AF32, int BF32, int MODE>
__device__ __forceinline__ void gemm_core(const void* Ap, const void* Bp, void* Cout,
                                          int bm, int bn, int bz, int N, int K, int tid,
                                          short* As, short* Bs) {
  constexpr int SA = AF32 ? 72 : 64;
  constexpr int SB = BF32 ? 72 : 64;
  const int wave = tid >> 6, lane = tid & 63, quad = lane >> 4, l16 = lane & 15;
  const int wm = (wave >> 1) * 64, wn = (wave & 1) * 64;
  const float* A32 = (const float*)Ap + (long)bm * 128 * K;
  const short* A16 = (const short*)Ap + (long)bm * 128 * K;
  const float* B32 = (const float*)Bp + (long)bn * 128 * K;
  const short* B16 = (const short*)Bp + (long)bn * 128 * K;

  const f32x4 zero = {0.f, 0.f, 0.f, 0.f};
  f32x4 acc[4][4];
#pragma unroll
  for (int i = 0; i < 4; i++)
#pragma unroll
    for (int j = 0; j < 4; j++) acc[i][j] = zero;

  f32x4 ar[8], br[8];
  if (AF32) { ldf32(A32, K, 0, tid, ar); wrf32(As, SA, tid, ar); }
  else ldbf16(A16, K, 0, tid, As);
  if (BF32) { ldf32(B32, K, 0, tid, br); wrf32(Bs, SB, tid, br); }
  else ldbf16(B16, K, 0, tid, Bs);
  __syncthreads();

  const int NT = K >> 6;
  int cur = 0;
  for (int t = 0; t < NT; ++t) {
    short* Ac = As + cur * 128 * SA;
    short* Bc = Bs + cur * 128 * SB;
    short* An = As + (cur ^ 1) * 128 * SA;
    short* Bn = Bs + (cur ^ 1) * 128 * SB;
    const bool more = (t + 1 < NT);
    if (more) {
      if (AF32) ldf32(A32, K, (t + 1) * 64, tid, ar);
      else ldbf16(A16, K, (t + 1) * 64, tid, An);
      if (BF32) ldf32(B32, K, (t + 1) * 64, tid, br);
      else ldbf16(B16, K, (t + 1) * 64, tid, Bn);
    }
#pragma unroll
    for (int kk = 0; kk < 64; kk += 32) {
      short8 af[4], bf[4];
#pragma unroll
      for (int i = 0; i < 4; i++) af[i] = *(const short8*)&Ac[(wm + i * 16 + l16) * SA + kk + quad * 8];
#pragma unroll
      for (int j = 0; j < 4; j++) bf[j] = *(const short8*)&Bc[(wn + j * 16 + l16) * SB + kk + quad * 8];
#pragma unroll
      for (int i = 0; i < 4; i++)
#pragma unroll
        for (int j = 0; j < 4; j++)
          acc[i][j] = __builtin_amdgcn_mfma_f32_16x16x32_bf16(af[i], bf[j], acc[i][j], 0, 0, 0);
    }
    if (more) {
      if (AF32) wrf32(An, SA, tid, ar);
      if (BF32) wrf32(Bn, SB, tid, br);
    }
    __syncthreads();
    cur ^= 1;
  }

#pragma unroll
  for (int i = 0; i < 4; i++)
#pragma unroll
    for (int j = 0; j < 4; j++)
#pragma unroll
      for (int r = 0; r < 4; r++) {
        const int grow = bm * 128 + wm + i * 16 + quad * 4 + r;
        const int gcol = bn * 128 + wn + j * 16 + l16;
        const float val = acc[i][j][r];
        if (MODE == 0) {
          const int b = grow >> 11, l = grow & 2047, hh = gcol >> 6, d = gcol & 63;
          ((short*)Cout)[((long)(b * 16 + hh) * 2048 + l) * 64 + d] = f2bf(val);
        } else if (MODE == 1) {
          ((short*)Cout)[((long)bz * 1024 + grow) * 2048 + gcol] = f2bf(val);
        } else {
          ((float*)Cout)[(long)grow * N + gcol] = val;
        }
      }
}

__global__ __launch_bounds__(256) void proj_fused(const float* __restrict__ q, const float* __restrict__ k,
                                                  const float* __restrict__ v,
                                                  const short* __restrict__ wqb, const short* __restrict__ wkb,
                                                  const short* __restrict__ wvb,
                                                  short* __restrict__ qh, short* __restrict__ kh,
                                                  short* __restrict__ vht) {
  __shared__ __align__(16) short As[2 * 128 * 72];
  __shared__ __align__(16) short Bs[2 * 128 * 72];
  const int id = blockIdx.x, tid = threadIdx.x;
  if (id < 512) {
    const int seg = id >> 8, lid = id & 255;
    gemm_core<1, 0, 0>(seg ? (const void*)k : (const void*)q,
                       seg ? (const void*)wkb : (const void*)wqb,
                       seg ? (void*)kh : (void*)qh,
                       lid & 31, lid >> 5, 0, 1024, 1024, tid, As, Bs);
  } else {
    const int lid = id - 512;
    const int bz = lid >> 7;
    gemm_core<0, 1, 1>(wvb, v + (long)bz * 2048 * 1024, vht,
                       lid & 7, (lid >> 3) & 15, bz, 2048, 1024, tid, As, Bs);
  }
}

__global__ __launch_bounds__(256) void gemm_final(const short* __restrict__ yhb, const short* __restrict__ fcb,
                                                  float* __restrict__ y) {
  __shared__ __align__(16) short As[2 * 128 * 72];
  __shared__ __align__(16) short Bs[2 * 128 * 72];
  gemm_core<0, 0, 2>(yhb, fcb, y, blockIdx.x, blockIdx.y, 0, 1024, 1024, threadIdx.x, As, Bs);
}

// attention: grid (32 qtiles, 16 heads, 2 batch), 256 threads (4 waves x 16 q-rows).
// Pass A: S=QK, p~=exp(s), l+=sums, PV with unnormalized p~ (scale by 1/l after).
// Pass B: recompute S, p=exp(s)/l, coalesced fp32 attn store via LDS transpose.
__global__ __launch_bounds__(256) void attn_kernel(const short* __restrict__ qh, const short* __restrict__ kh,
                                                   const short* __restrict__ vht,
                                                   float* __restrict__ attn_out, short* __restrict__ yhb) {
  __shared__ __align__(16) char smem[2 * 9216 + 17408];  // k_s | v_s | p (bf16 A / f32 B)
  short (*k_s)[72] = (short(*)[72])smem;
  short (*v_s)[72] = (short(*)[72])(smem + 9216);
  short (*p_s)[72] = (short(*)[72])(smem + 18432);
  float (*p_f)[68] = (float(*)[68])(smem + 18432);
  constexpr float SCALE = 0.022097086912079608f;  // 1/sqrt(2048)

  const int qb = blockIdx.x, h = blockIdx.y, b = blockIdx.z;
  const long bh = b * 16 + h;
  const short* Q = qh + bh * (2048L * 64) + (long)qb * 64 * 64;
  const short* Kp = kh + bh * (2048L * 64);
  const short* Vt = vht + bh * (64L * 2048);
  float* attnp = attn_out + bh * (2048L * 2048) + (long)qb * 64 * 2048;

  const int tid = threadIdx.x;
  const int wave = tid >> 6, lane = tid & 63, quad = lane >> 4, l16 = lane & 15;
  const int myrow0 = wave * 16;
  const int srow = tid >> 2, sch = (tid & 3) * 16;  // staging map: 64 rows x 4 chunks
  const f32x4 zero = {0.f, 0.f, 0.f, 0.f};

  // Q fragments straight from global, held in registers for both passes
  const short8 qa0 = *(const short8*)(Q + (myrow0 + l16) * 64 + quad * 8);
  const short8 qa1 = *(const short8*)(Q + (myrow0 + l16) * 64 + 32 + quad * 8);

  float lrow[4] = {0.f, 0.f, 0.f, 0.f};
  f32x4 oacc[4];
#pragma unroll
  for (int nt = 0; nt < 4; ++nt) oacc[nt] = zero;

  // ---- pass A: K+V staged; QK -> p~ -> {l accum, PV} ----
  *(short8*)&k_s[srow][sch] = *(const short8*)(Kp + srow * 64 + sch);
  *(short8*)&k_s[srow][sch + 8] = *(const short8*)(Kp + srow * 64 + sch + 8);
  *(short8*)&v_s[srow][sch] = *(const short8*)(Vt + (long)srow * 2048 + sch);
  *(short8*)&v_s[srow][sch + 8] = *(const short8*)(Vt + (long)srow * 2048 + sch + 8);
  __syncthreads();
  for (int kt = 0; kt < 32; ++kt) {
    short8 nk0, nk1, nv0, nv1;
    if (kt < 31) {  // prefetch next K/V tiles to regs; latency hides under QK+PV
      const short* Kn = Kp + ((kt + 1) * 64 + srow) * 64 + sch;
      nk0 = *(const short8*)(Kn);
      nk1 = *(const short8*)(Kn + 8);
      const short* Vn = Vt + (long)srow * 2048 + (kt + 1) * 64 + sch;
      nv0 = *(const short8*)(Vn);
      nv1 = *(const short8*)(Vn + 8);
    }
#pragma unroll
    for (int nt = 0; nt < 4; ++nt) {
      short8 b0 = *(const short8*)&k_s[nt * 16 + l16][quad * 8];
      short8 b1 = *(const short8*)&k_s[nt * 16 + l16][32 + quad * 8];
      f32x4 c = zero;
      c = __builtin_amdgcn_mfma_f32_16x16x32_bf16(qa0, b0, c, 0, 0, 0);
      c = __builtin_amdgcn_mfma_f32_16x16x32_bf16(qa1, b1, c, 0, 0, 0);
#pragma unroll
      for (int r = 0; r < 4; ++r) {
        const float p = __expf(c[r] * SCALE);   // unnormalized
        lrow[r] += p;
        p_s[myrow0 + quad * 4 + r][nt * 16 + l16] = f2bf(p);
      }
    }
    // p_s rows are wave-private -> no barrier needed before reading
    short8 pa0 = *(const short8*)&p_s[myrow0 + l16][quad * 8];
    short8 pa1 = *(const short8*)&p_s[myrow0 + l16][32 + quad * 8];
#pragma unroll
    for (int nt = 0; nt < 4; ++nt) {
      short8 vb0 = *(const short8*)&v_s[nt * 16 + l16][quad * 8];
      short8 vb1 = *(const short8*)&v_s[nt * 16 + l16][32 + quad * 8];
      oacc[nt] = __builtin_amdgcn_mfma_f32_16x16x32_bf16(pa0, vb0, oacc[nt], 0, 0, 0);
      oacc[nt] = __builtin_amdgcn_mfma_f32_16x16x32_bf16(pa1, vb1, oacc[nt], 0, 0, 0);
    }
    __syncthreads();  // all waves done reading k_s/v_s
    if (kt < 31) {
      *(short8*)&k_s[srow][sch] = nk0;
      *(short8*)&k_s[srow][sch + 8] = nk1;
      *(short8*)&v_s[srow][sch] = nv0;
      *(short8*)&v_s[srow][sch + 8] = nv1;
    }
    __syncthreads();  // staging complete
  }

  // row sums across the 16 lanes holding different columns of the same row
  float rinv[4];
#pragma unroll
  for (int r = 0; r < 4; ++r) {
    float l = lrow[r];
#pragma unroll
    for (int off = 1; off < 16; off <<= 1) l += __shfl_xor(l, off);
    rinv[r] = 1.0f / l;
  }

  // finish yh = (PV) / l
#pragma unroll
  for (int nt = 0; nt < 4; ++nt)
#pragma unroll
    for (int r = 0; r < 4; ++r) {
      const long l = (long)qb * 64 + myrow0 + quad * 4 + r;
      const int d = nt * 16 + l16;
      yhb[((long)b * 2048 + l) * 1024 + h * 64 + d] = f2bf(oacc[nt][r] * rinv[r]);
    }

  // ---- pass B: K-only staging (dbuf via k_s/v_s), coalesced attn writes ----
  const int prow_r = tid >> 2, pch = (tid & 3) * 16;     // transpose-read/store mapping
  float* attnrow = attnp + (long)prow_r * 2048 + pch;
  *(short8*)&k_s[srow][sch] = *(const short8*)(Kp + srow * 64 + sch);
  *(short8*)&k_s[srow][sch + 8] = *(const short8*)(Kp + srow * 64 + sch + 8);
  __syncthreads();
  for (int kt = 0; kt < 32; ++kt) {
    short(*cb)[72] = (kt & 1) ? v_s : k_s;
    short(*nb)[72] = (kt & 1) ? k_s : v_s;
    short8 n0, n1;
    if (kt < 31) {
      const short* Kn = Kp + ((kt + 1) * 64 + srow) * 64 + sch;
      n0 = *(const short8*)(Kn);
      n1 = *(const short8*)(Kn + 8);
    }
#pragma unroll
    for (int nt = 0; nt < 4; ++nt) {
      short8 b0 = *(const short8*)&cb[nt * 16 + l16][quad * 8];
      short8 b1 = *(const short8*)&cb[nt * 16 + l16][32 + quad * 8];
      f32x4 c = zero;
      c = __builtin_amdgcn_mfma_f32_16x16x32_bf16(qa0, b0, c, 0, 0, 0);
      c = __builtin_amdgcn_mfma_f32_16x16x32_bf16(qa1, b1, c, 0, 0, 0);
#pragma unroll
      for (int r = 0; r < 4; ++r)
        p_f[myrow0 + quad * 4 + r][nt * 16 + l16] = __expf(c[r] * SCALE) * rinv[r];
    }
    // transpose-read own wave's rows (wave-private), store 64B/thread contiguous
#pragma unroll
    for (int j = 0; j < 4; ++j) {
      const f32x4 x = *(const f32x4*)&p_f[prow_r][pch + j * 4];
      __builtin_nontemporal_store(x, (f32x4*)(attnrow + kt * 64 + j * 4));
    }
    if (kt < 31) {
      *(short8*)&nb[srow][sch] = n0;
      *(short8*)&nb[srow][sch + 8] = n1;
    }
    __syncthreads();
  }
}

extern "C" void kernel_launch(void* const* d_in, const int* in_sizes, int n_in,
                              void* d_out, int out_size, void* d_ws, size_t ws_size,
                              hipStream_t stream) {
  const float* q = (const float*)d_in[0];
  const float* k = (const float*)d_in[1];
  const float* v = (const float*)d_in[2];
  const float* wq = (const float*)d_in[3];
  const float* wk = (const float*)d_in[4];
  const float* wv = (const float*)d_in[5];
  const float* fcy = (const float*)d_in[6];

  float* y_out = (float*)d_out;                 // 2*2048*1024 fp32
  float* attn_out = (float*)d_out + 4194304;    // 2*16*2048*2048 fp32

  char* ws = (char*)d_ws;                       // total 41,943,040 B
  short* qh = (short*)(ws);                     // 8 MB  bf16 (b,h,l,d)
  short* kh = (short*)(ws + 8388608);           // 8 MB  bf16 (b,h,l,d)
  short* vht = (short*)(ws + 16777216);         // 8 MB  bf16 (b,h,d,l)
  short* yhb = (short*)(ws + 25165824);         // 8 MB  bf16 (b,l,h*64+d)
  short* wqb = (short*)(ws + 33554432);         // 2 MB  bf16
  short* wkb = (short*)(ws + 35651584);         // 2 MB
  short* wvb = (short*)(ws + 37748736);         // 2 MB
  short* fcb = (short*)(ws + 39845888);         // 2 MB

  cvt_w<<<2048, 256, 0, stream>>>(wq, wk, wv, fcy, wqb, wkb, wvb, fcb);
  proj_fused<<<768, 256, 0, stream>>>(q, k, v, wqb, wkb, wvb, qh, kh, vht);
  attn_kernel<<<dim3(32, 16, 2), 256, 0, stream>>>(qh, kh, vht, attn_out, yhb);
  gemm_final<<<dim3(32, 8), 256, 0, stream>>>(yhb, fcb, y_out);
}

// Round 3
// 799.808 us; speedup vs baseline: 1.9563x; 1.9563x over previous
//
#include <hip/hip_runtime.h>

typedef __attribute__((ext_vector_type(8))) short short8;
typedef __attribute__((ext_vector_type(4))) short short4v;
typedef __attribute__((ext_vector_type(4))) float f32x4;

__device__ __forceinline__ short f2bf(float f) {
  unsigned u = __float_as_uint(f);
  u += 0x7fff + ((u >> 16) & 1);   // round-to-nearest-even
  return (short)(u >> 16);
}

// async 16B global->LDS (dest = wave-uniform base + lane*16)
__device__ __forceinline__ void async16(const short* g, short* l) {
  __builtin_amdgcn_global_load_lds(
      (__attribute__((address_space(1))) unsigned int*)(g),
      (__attribute__((address_space(3))) unsigned int*)(l), 16, 0, 0);
}

// ---- one-shot weight conversion: 4 x (1024x1024) fp32 -> bf16 ----
__global__ __launch_bounds__(256) void cvt_w(const float* __restrict__ w0, const float* __restrict__ w1,
                                             const float* __restrict__ w2, const float* __restrict__ w3,
                                             short* __restrict__ o0, short* __restrict__ o1,
                                             short* __restrict__ o2, short* __restrict__ o3) {
  const int bid = blockIdx.x;
  const int seg = bid >> 9;  // 512 blocks per tensor
  const float* s = seg == 0 ? w0 : seg == 1 ? w1 : seg == 2 ? w2 : w3;
  short* d = seg == 0 ? o0 : seg == 1 ? o1 : seg == 2 ? o2 : o3;
  const int idx = ((bid & 511) * 256 + (int)threadIdx.x) * 8;
  float4 x = *(const float4*)(s + idx);
  float4 y = *(const float4*)(s + idx + 4);
  short8 t;
  t[0] = f2bf(x.x); t[1] = f2bf(x.y); t[2] = f2bf(x.z); t[3] = f2bf(x.w);
  t[4] = f2bf(y.x); t[5] = f2bf(y.y); t[6] = f2bf(y.z); t[7] = f2bf(y.w);
  *(short8*)(d + idx) = t;
}

// ---- GEMM staging helpers (128x64 K-tile) ----
__device__ __forceinline__ void ldf32(const float* src, int K, int kt, int tid, f32x4* r) {
  const int row = tid >> 4, c = (tid & 15) * 4;
  const float* p = src + (long)row * K + kt + c;
#pragma unroll
  for (int j = 0; j < 8; j++) r[j] = *(const f32x4*)(p + (long)(j * 16) * K);
}
__device__ __forceinline__ void wrf32(short* dst, int stride, int tid, const f32x4* r) {
  const int row = tid >> 4, c = (tid & 15) * 4;
#pragma unroll
  for (int j = 0; j < 8; j++) {
    short4v t;
    t[0] = f2bf(r[j][0]); t[1] = f2bf(r[j][1]); t[2] = f2bf(r[j][2]); t[3] = f2bf(r[j][3]);
    *(short4v*)&dst[(row + j * 16) * stride + c] = t;
  }
}
__device__ __forceinline__ void ldbf16(const short* src, int K, int kt, int tid, short* lds) {
  const int w = tid >> 6, l = tid & 63;
#pragma unroll
  for (int i = 0; i < 4; i++) {
    const int seg = i * 4 + w;           // 16 segments x 1KB
    const int o = seg * 1024 + l * 16;   // byte offset in 16KB tile
    const int row = o >> 7, col = (o & 127) >> 1;
    async16(src + (long)row * K + kt + col, lds + seg * 512);
  }
}

// C[m][n] = sum_k A[m][k]*B[n][k].  2-phase double-buffered, 1 barrier/K-step.
template <int AF32, int BF32, int MODE>
__device__ __forceinline__ void gemm_core(const void* Ap, const void* Bp, void* Cout,
                                          int bm, int bn, int bz, int N, int K, int tid,
                                          short* As, short* Bs) {
  constexpr int SA = AF32 ? 72 : 64;
  constexpr int SB = BF32 ? 72 : 64;
  const int wave = tid >> 6, lane = tid & 63, quad = lane >> 4, l16 = lane & 15;
  const int wm = (wave >> 1) * 64, wn = (wave & 1) * 64;
  const float* A32 = (const float*)Ap + (long)bm * 128 * K;
  const short* A16 = (const short*)Ap + (long)bm * 128 * K;
  const float* B32 = (const float*)Bp + (long)bn * 128 * K;
  const short* B16 = (const short*)Bp + (long)bn * 128 * K;

  const f32x4 zero = {0.f, 0.f, 0.f, 0.f};
  f32x4 acc[4][4];
#pragma unroll
  for (int i = 0; i < 4; i++)
#pragma unroll
    for (int j = 0; j < 4; j++) acc[i][j] = zero;

  f32x4 ar[8], br[8];
  if (AF32) { ldf32(A32, K, 0, tid, ar); wrf32(As, SA, tid, ar); }
  else ldbf16(A16, K, 0, tid, As);
  if (BF32) { ldf32(B32, K, 0, tid, br); wrf32(Bs, SB, tid, br); }
  else ldbf16(B16, K, 0, tid, Bs);
  __syncthreads();

  const int NT = K >> 6;
  int cur = 0;
  for (int t = 0; t < NT; ++t) {
    short* Ac = As + cur * 128 * SA;
    short* Bc = Bs + cur * 128 * SB;
    short* An = As + (cur ^ 1) * 128 * SA;
    short* Bn = Bs + (cur ^ 1) * 128 * SB;
    const bool more = (t + 1 < NT);
    if (more) {
      if (AF32) ldf32(A32, K, (t + 1) * 64, tid, ar);
      else ldbf16(A16, K, (t + 1) * 64, tid, An);
      if (BF32) ldf32(B32, K, (t + 1) * 64, tid, br);
      else ldbf16(B16, K, (t + 1) * 64, tid, Bn);
    }
#pragma unroll
    for (int kk = 0; kk < 64; kk += 32) {
      short8 af[4], bf[4];
#pragma unroll
      for (int i = 0; i < 4; i++) af[i] = *(const short8*)&Ac[(wm + i * 16 + l16) * SA + kk + quad * 8];
#pragma unroll
      for (int j = 0; j < 4; j++) bf[j] = *(const short8*)&Bc[(wn + j * 16 + l16) * SB + kk + quad * 8];
#pragma unroll
      for (int i = 0; i < 4; i++)
#pragma unroll
        for (int j = 0; j < 4; j++)
          acc[i][j] = __builtin_amdgcn_mfma_f32_16x16x32_bf16(af[i], bf[j], acc[i][j], 0, 0, 0);
    }
    if (more) {
      if (AF32) wrf32(An, SA, tid, ar);
      if (BF32) wrf32(Bn, SB, tid, br);
    }
    __syncthreads();
    cur ^= 1;
  }

#pragma unroll
  for (int i = 0; i < 4; i++)
#pragma unroll
    for (int j = 0; j < 4; j++)
#pragma unroll
      for (int r = 0; r < 4; r++) {
        const int grow = bm * 128 + wm + i * 16 + quad * 4 + r;
        const int gcol = bn * 128 + wn + j * 16 + l16;
        const float val = acc[i][j][r];
        if (MODE == 0) {
          const int b = grow >> 11, l = grow & 2047, hh = gcol >> 6, d = gcol & 63;
          ((short*)Cout)[((long)(b * 16 + hh) * 2048 + l) * 64 + d] = f2bf(val);
        } else if (MODE == 1) {
          ((short*)Cout)[((long)bz * 1024 + grow) * 2048 + gcol] = f2bf(val);
        } else {
          ((float*)Cout)[(long)grow * N + gcol] = val;
        }
      }
}

// 768 blocks; XCD-gather swizzle (768 = 8 XCDs x 96) + A-tile-major ordering so the
// 8 blocks sharing one fp32 activation tile are consecutive logical ids on ONE XCD.
__global__ __launch_bounds__(256) void proj_fused(const float* __restrict__ q, const float* __restrict__ k,
                                                  const float* __restrict__ v,
                                                  const short* __restrict__ wqb, const short* __restrict__ wkb,
                                                  const short* __restrict__ wvb,
                                                  short* __restrict__ qh, short* __restrict__ kh,
                                                  short* __restrict__ vht) {
  __shared__ __align__(16) short As[2 * 128 * 72];
  __shared__ __align__(16) short Bs[2 * 128 * 72];
  const int p = blockIdx.x, tid = threadIdx.x;
  const int id = (p & 7) * 96 + (p >> 3);   // physical->logical (bijective)
  if (id < 512) {                           // Q/K proj: A=fp32 act (shared by 8 bn), B=bf16 weight
    const int seg = id >> 8, t = id & 255;
    const int bm = t >> 3, bn = t & 7;      // bn fastest -> A-tile shared by consecutive ids
    gemm_core<1, 0, 0>(seg ? (const void*)k : (const void*)q,
                       seg ? (const void*)wkb : (const void*)wqb,
                       seg ? (void*)kh : (void*)qh,
                       bm, bn, 0, 1024, 1024, tid, As, Bs);
  } else {                                  // V proj: B=fp32 act (shared by 8 bm), A=bf16 weight
    const int lid = id - 512;
    const int bz = lid >> 7, t = lid & 127;
    gemm_core<0, 1, 1>(wvb, v + (long)bz * 2048 * 1024, vht,
                       t & 7, t >> 3, bz, 2048, 1024, tid, As, Bs);
  }
}

// 256 blocks 1-D; XCD-gather (256 = 8 x 32), bn fastest so A-tile-sharing blocks colocate.
__global__ __launch_bounds__(256) void gemm_final(const short* __restrict__ yhb, const short* __restrict__ fcb,
                                                  float* __restrict__ y) {
  __shared__ __align__(16) short As[2 * 128 * 72];
  __shared__ __align__(16) short Bs[2 * 128 * 72];
  const int p = blockIdx.x;
  const int id = (p & 7) * 32 + (p >> 3);
  gemm_core<0, 0, 2>(yhb, fcb, y, id >> 3, id & 7, 0, 1024, 1024, threadIdx.x, As, Bs);
}

// attention: grid (32 qtiles, 16 heads, 2 batch), 256 threads (4 waves x 16 q-rows).
// Pass A: S=QK, p~=exp(s), l+=sums, PV with unnormalized p~ (scale by 1/l after).
// Pass B: recompute S, p=exp(s)/l, direct NT dword stores (16 lanes = full 64B segment).
__global__ __launch_bounds__(256) void attn_kernel(const short* __restrict__ qh, const short* __restrict__ kh,
                                                   const short* __restrict__ vht,
                                                   float* __restrict__ attn_out, short* __restrict__ yhb) {
  __shared__ __align__(16) short k_s[64][72];
  __shared__ __align__(16) short v_s[64][72];
  __shared__ __align__(16) short p_s[64][72];
  constexpr float SCALE = 0.022097086912079608f;  // 1/sqrt(2048)

  const int qb = blockIdx.x, h = blockIdx.y, b = blockIdx.z;
  const long bh = b * 16 + h;
  const short* Q = qh + bh * (2048L * 64) + (long)qb * 64 * 64;
  const short* Kp = kh + bh * (2048L * 64);
  const short* Vt = vht + bh * (64L * 2048);
  float* attnp = attn_out + bh * (2048L * 2048) + (long)qb * 64 * 2048;

  const int tid = threadIdx.x;
  const int wave = tid >> 6, lane = tid & 63, quad = lane >> 4, l16 = lane & 15;
  const int myrow0 = wave * 16;
  const int srow = tid >> 2, sch = (tid & 3) * 16;  // staging map: 64 rows x 4 chunks
  const f32x4 zero = {0.f, 0.f, 0.f, 0.f};

  // Q fragments straight from global, held in registers for both passes
  const short8 qa0 = *(const short8*)(Q + (myrow0 + l16) * 64 + quad * 8);
  const short8 qa1 = *(const short8*)(Q + (myrow0 + l16) * 64 + 32 + quad * 8);

  float lrow[4] = {0.f, 0.f, 0.f, 0.f};
  f32x4 oacc[4];
#pragma unroll
  for (int nt = 0; nt < 4; ++nt) oacc[nt] = zero;

  // ---- pass A: K+V staged; QK -> p~ -> {l accum, PV} ----
  *(short8*)&k_s[srow][sch] = *(const short8*)(Kp + srow * 64 + sch);
  *(short8*)&k_s[srow][sch + 8] = *(const short8*)(Kp + srow * 64 + sch + 8);
  *(short8*)&v_s[srow][sch] = *(const short8*)(Vt + (long)srow * 2048 + sch);
  *(short8*)&v_s[srow][sch + 8] = *(const short8*)(Vt + (long)srow * 2048 + sch + 8);
  __syncthreads();
  for (int kt = 0; kt < 32; ++kt) {
    short8 nk0, nk1, nv0, nv1;
    if (kt < 31) {  // prefetch next K/V tiles to regs; latency hides under QK+PV
      const short* Kn = Kp + ((kt + 1) * 64 + srow) * 64 + sch;
      nk0 = *(const short8*)(Kn);
      nk1 = *(const short8*)(Kn + 8);
      const short* Vn = Vt + (long)srow * 2048 + (kt + 1) * 64 + sch;
      nv0 = *(const short8*)(Vn);
      nv1 = *(const short8*)(Vn + 8);
    }
#pragma unroll
    for (int nt = 0; nt < 4; ++nt) {
      short8 b0 = *(const short8*)&k_s[nt * 16 + l16][quad * 8];
      short8 b1 = *(const short8*)&k_s[nt * 16 + l16][32 + quad * 8];
      f32x4 c = zero;
      c = __builtin_amdgcn_mfma_f32_16x16x32_bf16(qa0, b0, c, 0, 0, 0);
      c = __builtin_amdgcn_mfma_f32_16x16x32_bf16(qa1, b1, c, 0, 0, 0);
#pragma unroll
      for (int r = 0; r < 4; ++r) {
        const float p = __expf(c[r] * SCALE);   // unnormalized
        lrow[r] += p;
        p_s[myrow0 + quad * 4 + r][nt * 16 + l16] = f2bf(p);
      }
    }
    // p_s rows are wave-private -> no barrier needed before reading
    short8 pa0 = *(const short8*)&p_s[myrow0 + l16][quad * 8];
    short8 pa1 = *(const short8*)&p_s[myrow0 + l16][32 + quad * 8];
#pragma unroll
    for (int nt = 0; nt < 4; ++nt) {
      short8 vb0 = *(const short8*)&v_s[nt * 16 + l16][quad * 8];
      short8 vb1 = *(const short8*)&v_s[nt * 16 + l16][32 + quad * 8];
      oacc[nt] = __builtin_amdgcn_mfma_f32_16x16x32_bf16(pa0, vb0, oacc[nt], 0, 0, 0);
      oacc[nt] = __builtin_amdgcn_mfma_f32_16x16x32_bf16(pa1, vb1, oacc[nt], 0, 0, 0);
    }
    __syncthreads();  // all waves done reading k_s/v_s
    if (kt < 31) {
      *(short8*)&k_s[srow][sch] = nk0;
      *(short8*)&k_s[srow][sch + 8] = nk1;
      *(short8*)&v_s[srow][sch] = nv0;
      *(short8*)&v_s[srow][sch + 8] = nv1;
    }
    __syncthreads();  // staging complete
  }

  // row sums across the 16 lanes holding different columns of the same row
  float rinv[4];
#pragma unroll
  for (int r = 0; r < 4; ++r) {
    float l = lrow[r];
#pragma unroll
    for (int off = 1; off < 16; off <<= 1) l += __shfl_xor(l, off);
    rinv[r] = 1.0f / l;
  }

  // finish yh = (PV) / l
#pragma unroll
  for (int nt = 0; nt < 4; ++nt)
#pragma unroll
    for (int r = 0; r < 4; ++r) {
      const long l = (long)qb * 64 + myrow0 + quad * 4 + r;
      const int d = nt * 16 + l16;
      yhb[((long)b * 2048 + l) * 1024 + h * 64 + d] = f2bf(oacc[nt][r] * rinv[r]);
    }

  // ---- pass B: K-only staging (dbuf via k_s/v_s), direct NT dword stores ----
  *(short8*)&k_s[srow][sch] = *(const short8*)(Kp + srow * 64 + sch);
  *(short8*)&k_s[srow][sch + 8] = *(const short8*)(Kp + srow * 64 + sch + 8);
  __syncthreads();
  for (int kt = 0; kt < 32; ++kt) {
    short(*cb)[72] = (kt & 1) ? v_s : k_s;
    short(*nb)[72] = (kt & 1) ? k_s : v_s;
    short8 n0, n1;
    if (kt < 31) {
      const short* Kn = Kp + ((kt + 1) * 64 + srow) * 64 + sch;
      n0 = *(const short8*)(Kn);
      n1 = *(const short8*)(Kn + 8);
    }
#pragma unroll
    for (int nt = 0; nt < 4; ++nt) {
      short8 b0 = *(const short8*)&cb[nt * 16 + l16][quad * 8];
      short8 b1 = *(const short8*)&cb[nt * 16 + l16][32 + quad * 8];
      f32x4 c = zero;
      c = __builtin_amdgcn_mfma_f32_16x16x32_bf16(qa0, b0, c, 0, 0, 0);
      c = __builtin_amdgcn_mfma_f32_16x16x32_bf16(qa1, b1, c, 0, 0, 0);
#pragma unroll
      for (int r = 0; r < 4; ++r) {
        const float pv = __expf(c[r] * SCALE) * rinv[r];
        // 16 lanes (l16) write 16 consecutive dwords -> full 64B segment per instr
        __builtin_nontemporal_store(
            pv, &attnp[(long)(myrow0 + quad * 4 + r) * 2048 + kt * 64 + nt * 16 + l16]);
      }
    }
    if (kt < 31) {
      *(short8*)&nb[srow][sch] = n0;
      *(short8*)&nb[srow][sch + 8] = n1;
    }
    __syncthreads();
  }
}

extern "C" void kernel_launch(void* const* d_in, const int* in_sizes, int n_in,
                              void* d_out, int out_size, void* d_ws, size_t ws_size,
                              hipStream_t stream) {
  const float* q = (const float*)d_in[0];
  const float* k = (const float*)d_in[1];
  const float* v = (const float*)d_in[2];
  const float* wq = (const float*)d_in[3];
  const float* wk = (const float*)d_in[4];
  const float* wv = (const float*)d_in[5];
  const float* fcy = (const float*)d_in[6];

  float* y_out = (float*)d_out;                 // 2*2048*1024 fp32
  float* attn_out = (float*)d_out + 4194304;    // 2*16*2048*2048 fp32

  char* ws = (char*)d_ws;                       // total 41,943,040 B
  short* qh = (short*)(ws);                     // 8 MB  bf16 (b,h,l,d)
  short* kh = (short*)(ws + 8388608);           // 8 MB  bf16 (b,h,l,d)
  short* vht = (short*)(ws + 16777216);         // 8 MB  bf16 (b,h,d,l)
  short* yhb = (short*)(ws + 25165824);         // 8 MB  bf16 (b,l,h*64+d)
  short* wqb = (short*)(ws + 33554432);         // 2 MB  bf16
  short* wkb = (short*)(ws + 35651584);         // 2 MB
  short* wvb = (short*)(ws + 37748736);         // 2 MB
  short* fcb = (short*)(ws + 39845888);         // 2 MB

  cvt_w<<<2048, 256, 0, stream>>>(wq, wk, wv, fcy, wqb, wkb, wvb, fcb);
  proj_fused<<<768, 256, 0, stream>>>(q, k, v, wqb, wkb, wvb, qh, kh, vht);
  attn_kernel<<<dim3(32, 16, 2), 256, 0, stream>>>(qh, kh, vht, attn_out, yhb);
  gemm_final<<<dim3(256), 256, 0, stream>>>(yhb, fcb, y_out);
}

// Round 5
// 764.102 us; speedup vs baseline: 2.0477x; 1.0467x over previous
//
#include <hip/hip_runtime.h>

typedef __attribute__((ext_vector_type(8))) short short8;
typedef __attribute__((ext_vector_type(4))) float f32x4;

__device__ __forceinline__ short f2bf(float f) {
  unsigned u = __float_as_uint(f);
  u += 0x7fff + ((u >> 16) & 1);   // round-to-nearest-even
  return (short)(u >> 16);
}

// async 16B global->LDS (dest = wave-uniform base + lane*16)
__device__ __forceinline__ void async16(const short* g, short* l) {
  __builtin_amdgcn_global_load_lds(
      (__attribute__((address_space(1))) unsigned int*)(g),
      (__attribute__((address_space(3))) unsigned int*)(l), 16, 0, 0);
}

// ---- fp32->bf16 bulk convert: NSEG segments, each seg = src[i], dst[i], nblk[i] blocks ----
// cvt1: 4 weights (512 blk each) + q,k (2048 blk each) = 6144 blocks
__global__ __launch_bounds__(256) void cvt1(
    const float* __restrict__ w0, const float* __restrict__ w1,
    const float* __restrict__ w2, const float* __restrict__ w3,
    const float* __restrict__ qa, const float* __restrict__ ka,
    short* __restrict__ ow0, short* __restrict__ ow1, short* __restrict__ ow2,
    short* __restrict__ ow3, short* __restrict__ oq, short* __restrict__ ok) {
  const int bid = blockIdx.x;
  const float* s;
  short* d;
  long idx;
  if (bid < 2048) {            // weights: 4 x 1M elems
    const int seg = bid >> 9;
    s = seg == 0 ? w0 : seg == 1 ? w1 : seg == 2 ? w2 : w3;
    d = seg == 0 ? ow0 : seg == 1 ? ow1 : seg == 2 ? ow2 : ow3;
    idx = (long)(bid & 511) * 2048 + (long)threadIdx.x * 8;
  } else {                     // q,k: 2 x 4M elems
    const int t = bid - 2048;
    const int seg = t >> 11;
    s = seg == 0 ? qa : ka;
    d = seg == 0 ? oq : ok;
    idx = (long)(t & 2047) * 2048 + (long)threadIdx.x * 8;
  }
  const float4 x = *(const float4*)(s + idx);
  const float4 y = *(const float4*)(s + idx + 4);
  short8 t8;
  t8[0] = f2bf(x.x); t8[1] = f2bf(x.y); t8[2] = f2bf(x.z); t8[3] = f2bf(x.w);
  t8[4] = f2bf(y.x); t8[5] = f2bf(y.y); t8[6] = f2bf(y.z); t8[7] = f2bf(y.w);
  *(short8*)(d + idx) = t8;
}

// cvt2: v only (4M elems, 2048 blocks)
__global__ __launch_bounds__(256) void cvt2(const float* __restrict__ va, short* __restrict__ ov) {
  const long idx = (long)blockIdx.x * 2048 + (long)threadIdx.x * 8;
  const float4 x = *(const float4*)(va + idx);
  const float4 y = *(const float4*)(va + idx + 4);
  short8 t8;
  t8[0] = f2bf(x.x); t8[1] = f2bf(x.y); t8[2] = f2bf(x.z); t8[3] = f2bf(x.w);
  t8[4] = f2bf(y.x); t8[5] = f2bf(y.y); t8[6] = f2bf(y.z); t8[7] = f2bf(y.w);
  *(short8*)(ov + idx) = t8;
}

// stage a 128x64 bf16 K-tile (16 KB) linearly into LDS via global_load_lds
__device__ __forceinline__ void ldbf16(const short* src, int K, int kt, int tid, short* lds) {
  const int w = tid >> 6, l = tid & 63;
#pragma unroll
  for (int i = 0; i < 4; i++) {
    const int seg = i * 4 + w;           // 16 segments x 1KB
    const int o = seg * 1024 + l * 16;   // byte offset in 16KB tile
    const int row = o >> 7, col = (o & 127) >> 1;
    async16(src + (long)row * K + kt + col, lds + seg * 512);
  }
}

// C[m][n] = sum_k A[m][k]*B[n][k], all-bf16, m97 structure: single-buffered
// [128][64] linear LDS tiles, global_load_lds staging, 2 barriers/K-step.
// MODE 0: bf16 out ((b*16+h)*2048+l)*64+d | MODE 1: bf16 out (bz*1024+m)*2048+n | MODE 2: fp32 m*N+n
template <int MODE>
__device__ __forceinline__ void gemm_bf(const short* Aall, const short* Ball, void* Cout,
                                        int bm, int bn, int bz, int N, int K, int tid,
                                        short* As, short* Bs) {
  const int wave = tid >> 6, lane = tid & 63, quad = lane >> 4, l16 = lane & 15;
  const int wm = (wave >> 1) * 64, wn = (wave & 1) * 64;
  const short* A = Aall + (long)bm * 128 * K;
  const short* B = Ball + (long)bn * 128 * K;

  const f32x4 zero = {0.f, 0.f, 0.f, 0.f};
  f32x4 acc[4][4];
#pragma unroll
  for (int i = 0; i < 4; i++)
#pragma unroll
    for (int j = 0; j < 4; j++) acc[i][j] = zero;

  for (int kt = 0; kt < K; kt += 64) {
    __syncthreads();                 // prior compute done reading LDS
    ldbf16(A, K, kt, tid, As);
    ldbf16(B, K, kt, tid, Bs);
    __syncthreads();                 // staging drained (compiler emits vmcnt(0))
#pragma unroll
    for (int kk = 0; kk < 64; kk += 32) {
      short8 af[4], bf[4];
#pragma unroll
      for (int i = 0; i < 4; i++) af[i] = *(const short8*)&As[(wm + i * 16 + l16) * 64 + kk + quad * 8];
#pragma unroll
      for (int j = 0; j < 4; j++) bf[j] = *(const short8*)&Bs[(wn + j * 16 + l16) * 64 + kk + quad * 8];
#pragma unroll
      for (int i = 0; i < 4; i++)
#pragma unroll
        for (int j = 0; j < 4; j++)
          acc[i][j] = __builtin_amdgcn_mfma_f32_16x16x32_bf16(af[i], bf[j], acc[i][j], 0, 0, 0);
    }
  }

#pragma unroll
  for (int i = 0; i < 4; i++)
#pragma unroll
    for (int j = 0; j < 4; j++)
#pragma unroll
      for (int r = 0; r < 4; r++) {
        const int grow = bm * 128 + wm + i * 16 + quad * 4 + r;
        const int gcol = bn * 128 + wn + j * 16 + l16;
        const float val = acc[i][j][r];
        if (MODE == 0) {
          const int b = grow >> 11, l = grow & 2047, hh = gcol >> 6, d = gcol & 63;
          ((short*)Cout)[((long)(b * 16 + hh) * 2048 + l) * 64 + d] = f2bf(val);
        } else if (MODE == 1) {
          ((short*)Cout)[((long)bz * 1024 + grow) * 2048 + gcol] = f2bf(val);
        } else {
          ((float*)Cout)[(long)grow * N + gcol] = val;
        }
      }
}

// Q/K projections: 512 blocks (2/CU). XCD-gather swizzle (512 = 8*64), bn fastest.
__global__ __launch_bounds__(256, 3) void proj_qk(
    const short* __restrict__ qb, const short* __restrict__ kb,
    const short* __restrict__ wqb, const short* __restrict__ wkb,
    short* __restrict__ qh, short* __restrict__ kh) {
  __shared__ __align__(16) short As[128 * 64];
  __shared__ __align__(16) short Bs[128 * 64];
  const int p = blockIdx.x, tid = threadIdx.x;
  const int id = (p & 7) * 64 + (p >> 3);
  const int seg = id >> 8, t = id & 255;
  gemm_bf<0>(seg ? kb : qb, seg ? wkb : wqb, seg ? (void*)kh : (void*)qh,
             t >> 3, t & 7, 0, 1024, 1024, tid, As, Bs);
}

// V projection (transposed out): 256 blocks. 256 = 8*32 swizzle.
__global__ __launch_bounds__(256, 3) void proj_v(
    const short* __restrict__ vb, const short* __restrict__ wvb, short* __restrict__ vht) {
  __shared__ __align__(16) short As[128 * 64];
  __shared__ __align__(16) short Bs[128 * 64];
  const int p = blockIdx.x, tid = threadIdx.x;
  const int id = (p & 7) * 32 + (p >> 3);
  const int bz = id >> 7, t = id & 127;
  gemm_bf<1>(wvb, vb + (long)bz * 2048 * 1024, vht, t & 7, t >> 3, bz, 2048, 1024, tid, As, Bs);
}

__global__ __launch_bounds__(256, 3) void gemm_final(const short* __restrict__ yhb,
                                                     const short* __restrict__ fcb,
                                                     float* __restrict__ y) {
  __shared__ __align__(16) short As[128 * 64];
  __shared__ __align__(16) short Bs[128 * 64];
  const int p = blockIdx.x;
  const int id = (p & 7) * 32 + (p >> 3);   // 256 = 8*32
  gemm_bf<2>(yhb, fcb, y, id >> 3, id & 7, 0, 1024, 1024, threadIdx.x, As, Bs);
}

// attention: unchanged from round 3 (grid (32,16,2), 256 threads, 4 blocks/CU).
__global__ __launch_bounds__(256, 4) void attn_kernel(const short* __restrict__ qh,
                                                      const short* __restrict__ kh,
                                                      const short* __restrict__ vht,
                                                      float* __restrict__ attn_out,
                                                      short* __restrict__ yhb) {
  __shared__ __align__(16) short k_s[64][72];
  __shared__ __align__(16) short v_s[64][72];
  __shared__ __align__(16) short p_s[64][72];
  constexpr float SCALE = 0.022097086912079608f;  // 1/sqrt(2048)

  const int qb = blockIdx.x, h = blockIdx.y, b = blockIdx.z;
  const long bh = b * 16 + h;
  const short* Q = qh + bh * (2048L * 64) + (long)qb * 64 * 64;
  const short* Kp = kh + bh * (2048L * 64);
  const short* Vt = vht + bh * (64L * 2048);
  float* attnp = attn_out + bh * (2048L * 2048) + (long)qb * 64 * 2048;

  const int tid = threadIdx.x;
  const int wave = tid >> 6, lane = tid & 63, quad = lane >> 4, l16 = lane & 15;
  const int myrow0 = wave * 16;
  const int srow = tid >> 2, sch = (tid & 3) * 16;
  const f32x4 zero = {0.f, 0.f, 0.f, 0.f};

  const short8 qa0 = *(const short8*)(Q + (myrow0 + l16) * 64 + quad * 8);
  const short8 qa1 = *(const short8*)(Q + (myrow0 + l16) * 64 + 32 + quad * 8);

  float lrow[4] = {0.f, 0.f, 0.f, 0.f};
  f32x4 oacc[4];
#pragma unroll
  for (int nt = 0; nt < 4; ++nt) oacc[nt] = zero;

  // ---- pass A: K+V staged; QK -> p~ -> {l accum, PV} ----
  *(short8*)&k_s[srow][sch] = *(const short8*)(Kp + srow * 64 + sch);
  *(short8*)&k_s[srow][sch + 8] = *(const short8*)(Kp + srow * 64 + sch + 8);
  *(short8*)&v_s[srow][sch] = *(const short8*)(Vt + (long)srow * 2048 + sch);
  *(short8*)&v_s[srow][sch + 8] = *(const short8*)(Vt + (long)srow * 2048 + sch + 8);
  __syncthreads();
  for (int kt = 0; kt < 32; ++kt) {
    short8 nk0, nk1, nv0, nv1;
    if (kt < 31) {
      const short* Kn = Kp + ((kt + 1) * 64 + srow) * 64 + sch;
      nk0 = *(const short8*)(Kn);
      nk1 = *(const short8*)(Kn + 8);
      const short* Vn = Vt + (long)srow * 2048 + (kt + 1) * 64 + sch;
      nv0 = *(const short8*)(Vn);
      nv1 = *(const short8*)(Vn + 8);
    }
#pragma unroll
    for (int nt = 0; nt < 4; ++nt) {
      short8 b0 = *(const short8*)&k_s[nt * 16 + l16][quad * 8];
      short8 b1 = *(const short8*)&k_s[nt * 16 + l16][32 + quad * 8];
      f32x4 c = zero;
      c = __builtin_amdgcn_mfma_f32_16x16x32_bf16(qa0, b0, c, 0, 0, 0);
      c = __builtin_amdgcn_mfma_f32_16x16x32_bf16(qa1, b1, c, 0, 0, 0);
#pragma unroll
      for (int r = 0; r < 4; ++r) {
        const float p = __expf(c[r] * SCALE);   // unnormalized
        lrow[r] += p;
        p_s[myrow0 + quad * 4 + r][nt * 16 + l16] = f2bf(p);
      }
    }
    short8 pa0 = *(const short8*)&p_s[myrow0 + l16][quad * 8];
    short8 pa1 = *(const short8*)&p_s[myrow0 + l16][32 + quad * 8];
#pragma unroll
    for (int nt = 0; nt < 4; ++nt) {
      short8 vb0 = *(const short8*)&v_s[nt * 16 + l16][quad * 8];
      short8 vb1 = *(const short8*)&v_s[nt * 16 + l16][32 + quad * 8];
      oacc[nt] = __builtin_amdgcn_mfma_f32_16x16x32_bf16(pa0, vb0, oacc[nt], 0, 0, 0);
      oacc[nt] = __builtin_amdgcn_mfma_f32_16x16x32_bf16(pa1, vb1, oacc[nt], 0, 0, 0);
    }
    __syncthreads();
    if (kt < 31) {
      *(short8*)&k_s[srow][sch] = nk0;
      *(short8*)&k_s[srow][sch + 8] = nk1;
      *(short8*)&v_s[srow][sch] = nv0;
      *(short8*)&v_s[srow][sch + 8] = nv1;
    }
    __syncthreads();
  }

  float rinv[4];
#pragma unroll
  for (int r = 0; r < 4; ++r) {
    float l = lrow[r];
#pragma unroll
    for (int off = 1; off < 16; off <<= 1) l += __shfl_xor(l, off);
    rinv[r] = 1.0f / l;
  }

#pragma unroll
  for (int nt = 0; nt < 4; ++nt)
#pragma unroll
    for (int r = 0; r < 4; ++r) {
      const long l = (long)qb * 64 + myrow0 + quad * 4 + r;
      const int d = nt * 16 + l16;
      yhb[((long)b * 2048 + l) * 1024 + h * 64 + d] = f2bf(oacc[nt][r] * rinv[r]);
    }

  // ---- pass B: K-only staging (dbuf via k_s/v_s), direct NT dword stores ----
  *(short8*)&k_s[srow][sch] = *(const short8*)(Kp + srow * 64 + sch);
  *(short8*)&k_s[srow][sch + 8] = *(const short8*)(Kp + srow * 64 + sch + 8);
  __syncthreads();
  for (int kt = 0; kt < 32; ++kt) {
    short(*cb)[72] = (kt & 1) ? v_s : k_s;
    short(*nb)[72] = (kt & 1) ? k_s : v_s;
    short8 n0, n1;
    if (kt < 31) {
      const short* Kn = Kp + ((kt + 1) * 64 + srow) * 64 + sch;
      n0 = *(const short8*)(Kn);
      n1 = *(const short8*)(Kn + 8);
    }
#pragma unroll
    for (int nt = 0; nt < 4; ++nt) {
      short8 b0 = *(const short8*)&cb[nt * 16 + l16][quad * 8];
      short8 b1 = *(const short8*)&cb[nt * 16 + l16][32 + quad * 8];
      f32x4 c = zero;
      c = __builtin_amdgcn_mfma_f32_16x16x32_bf16(qa0, b0, c, 0, 0, 0);
      c = __builtin_amdgcn_mfma_f32_16x16x32_bf16(qa1, b1, c, 0, 0, 0);
#pragma unroll
      for (int r = 0; r < 4; ++r) {
        const float pv = __expf(c[r] * SCALE) * rinv[r];
        // 16 lanes (l16) write 16 consecutive dwords -> full 64B segment per instr
        __builtin_nontemporal_store(
            pv, &attnp[(long)(myrow0 + quad * 4 + r) * 2048 + kt * 64 + nt * 16 + l16]);
      }
    }
    if (kt < 31) {
      *(short8*)&nb[srow][sch] = n0;
      *(short8*)&nb[srow][sch + 8] = n1;
    }
    __syncthreads();
  }
}

extern "C" void kernel_launch(void* const* d_in, const int* in_sizes, int n_in,
                              void* d_out, int out_size, void* d_ws, size_t ws_size,
                              hipStream_t stream) {
  const float* q = (const float*)d_in[0];
  const float* k = (const float*)d_in[1];
  const float* v = (const float*)d_in[2];
  const float* wq = (const float*)d_in[3];
  const float* wk = (const float*)d_in[4];
  const float* wv = (const float*)d_in[5];
  const float* fcy = (const float*)d_in[6];

  float* y_out = (float*)d_out;                 // 2*2048*1024 fp32 (16 MB)
  float* attn_out = (float*)d_out + 4194304;    // 2*16*2048*2048 fp32 (537 MB)

  // workspace (40 MB) with time-multiplexed regions:
  //   [16,24) MB: qb16 during proj_qk  -> vht after proj_v
  //   [24,32) MB: kb16 during proj_qk  -> vb16 during proj_v -> yhb after attn
  char* ws = (char*)d_ws;
  short* qh  = (short*)(ws);                    // 8 MB  bf16 (b,h,l,d)
  short* kh  = (short*)(ws + 8388608);          // 8 MB  bf16 (b,h,l,d)
  short* vht = (short*)(ws + 16777216);         // 8 MB  bf16 (b,h,d,l)   [earlier: qb16]
  short* yhb = (short*)(ws + 25165824);         // 8 MB  bf16 (b,l,h*64+d)[earlier: kb16, vb16]
  short* wqb = (short*)(ws + 33554432);         // 2 MB  bf16
  short* wkb = (short*)(ws + 35651584);         // 2 MB
  short* wvb = (short*)(ws + 37748736);         // 2 MB
  short* fcb = (short*)(ws + 39845888);         // 2 MB
  short* qb16 = vht;                            // aliases (sequenced by stream order)
  short* kb16 = yhb;
  short* vb16 = yhb;

  cvt1<<<6144, 256, 0, stream>>>(wq, wk, wv, fcy, q, k, wqb, wkb, wvb, fcb, qb16, kb16);
  proj_qk<<<512, 256, 0, stream>>>(qb16, kb16, wqb, wkb, qh, kh);
  cvt2<<<2048, 256, 0, stream>>>(v, vb16);
  proj_v<<<256, 256, 0, stream>>>(vb16, wvb, vht);
  attn_kernel<<<dim3(32, 16, 2), 256, 0, stream>>>(qh, kh, vht, attn_out, yhb);
  gemm_final<<<dim3(256), 256, 0, stream>>>(yhb, fcb, y_out);
}